// Round 1
// baseline (755.779 us; speedup 1.0000x reference)
//
#include <hip/hip_runtime.h>
#include <stdint.h>

#define E_    8
#define D_    2048
#define I_    1408
#define TWOI_ 2816
#define N_    8192
#define BM    128
#define MAXTILES 72
#define MPAD  9216

typedef __bf16 bf16x8 __attribute__((ext_vector_type(8)));
typedef float  floatx4 __attribute__((ext_vector_type(4)));

// ---- meta layout (int offsets into ws) ----
#define M_CNT   0    // [8]
#define M_CUR   8    // [8]
#define M_PB    16   // padbase[8]
#define M_NT    24   // ntiles
#define M_RTE   32   // rt_expert[72]
#define M_RTR   104  // rt_row0[72]
#define M_RTV   176  // rt_nvalid[72]

// ---- ws byte offsets ----
#define OFF_PERM  4096ULL
#define OFF_WPAD  40960ULL
#define OFF_APAD  81920ULL
#define OFF_HPAD  37830656ULL
#define OFF_GU    63782912ULL
#define OFF_DN    156057600ULL
#define WS_NEED   202194944ULL

__device__ inline void gload16(const void* g, void* lds) {
  __builtin_amdgcn_global_load_lds(
      (__attribute__((address_space(1))) void*)g,
      (__attribute__((address_space(3))) void*)lds, 16, 0, 0);
}

__device__ inline unsigned short f2bf(float f) {
  unsigned int u = __builtin_bit_cast(unsigned int, f);
  u += 0x7fffu + ((u >> 16) & 1u);   // RNE; inputs finite
  return (unsigned short)(u >> 16);
}

// ---------------- routing ----------------
__global__ void k_hist(const int* __restrict__ ids, int* meta) {
  int i = blockIdx.x * 256 + threadIdx.x;
  if (i < N_) atomicAdd(&meta[M_CNT + ids[i]], 1);
}

__global__ void k_meta(int* meta) {
  if (threadIdx.x != 0) return;
  int padr = 0, tiles = 0;
  for (int e = 0; e < E_; ++e) {
    meta[M_PB + e] = padr;
    int c = meta[M_CNT + e];
    int nt = (c + BM - 1) / BM;
    for (int t = 0; t < nt; ++t) {
      meta[M_RTE + tiles] = e;
      meta[M_RTR + tiles] = padr + t * BM;
      int v = c - t * BM; if (v > BM) v = BM;
      meta[M_RTV + tiles] = v;
      tiles++;
    }
    padr += nt * BM;
  }
  meta[M_NT] = tiles;
}

__global__ void k_scatter(const int* __restrict__ ids, const float* __restrict__ w,
                          int* meta, int* perm, float* wpad) {
  int i = blockIdx.x * 256 + threadIdx.x;
  if (i >= N_) return;
  int e = ids[i];
  int pos = atomicAdd(&meta[M_CUR + e], 1);
  int r = meta[M_PB + e] + pos;
  perm[r] = i;
  wpad[r] = w[i];
}

// -------------- gather tokens -> bf16 (permuted, padded) --------------
__global__ void k_gather(const float* __restrict__ tokens, const int* __restrict__ perm,
                         unsigned short* __restrict__ apad) {
  int r = blockIdx.x;
  int t = perm[r];
  if (t < 0) return;  // pad row: leave as-is (finite poison)
  const float4* src = (const float4*)(tokens + (size_t)t * D_);
  uint4* dst = (uint4*)(apad + (size_t)r * D_);
  int i = threadIdx.x;  // 256 threads x 8 floats = 2048
  float4 a = src[i * 2], b = src[i * 2 + 1];
  union { unsigned short s[8]; uint4 v; } pk;
  pk.s[0] = f2bf(a.x); pk.s[1] = f2bf(a.y); pk.s[2] = f2bf(a.z); pk.s[3] = f2bf(a.w);
  pk.s[4] = f2bf(b.x); pk.s[5] = f2bf(b.y); pk.s[6] = f2bf(b.z); pk.s[7] = f2bf(b.w);
  dst[i] = pk.v;
}

// -------------- fp32 -> bf16 weight convert --------------
__global__ void k_cvt(const float* __restrict__ src, unsigned short* __restrict__ dst, int n8) {
  int i = blockIdx.x * 256 + threadIdx.x;  // each handles 8 elements
  if (i >= n8) return;
  const float4* s4 = (const float4*)src;
  float4 a = s4[i * 2], b = s4[i * 2 + 1];
  union { unsigned short s[8]; uint4 v; } pk;
  pk.s[0] = f2bf(a.x); pk.s[1] = f2bf(a.y); pk.s[2] = f2bf(a.z); pk.s[3] = f2bf(a.w);
  pk.s[4] = f2bf(b.x); pk.s[5] = f2bf(b.y); pk.s[6] = f2bf(b.z); pk.s[7] = f2bf(b.w);
  ((uint4*)dst)[i] = pk.v;
}

// -------------- GEMM1: fc1 = A @ gate_up^T, fused SwiGLU -> h (bf16) --------------
// block: 128 rows x 64 cols (gate AND up for those cols). 4 waves, each 32 rows x 64 cols.
__global__ __launch_bounds__(256) void k_gemm1(
    const unsigned short* __restrict__ apad,
    const unsigned short* __restrict__ gub,
    const float* __restrict__ wpad,
    const int* __restrict__ meta,
    unsigned short* __restrict__ hpad) {
  int rt = blockIdx.x;
  if (rt >= meta[M_NT]) return;
  int ct = blockIdx.y;  // 0..21
  int e = meta[M_RTE + rt], row0 = meta[M_RTR + rt], nv = meta[M_RTV + rt];

  __shared__ __attribute__((aligned(16))) __bf16 As[BM * 32];
  __shared__ __attribute__((aligned(16))) __bf16 Bgs[64 * 32];
  __shared__ __attribute__((aligned(16))) __bf16 Bus[64 * 32];

  int tid = threadIdx.x;
  int lane = tid & 63;
  int wave = __builtin_amdgcn_readfirstlane(tid >> 6);

  const __bf16* A  = (const __bf16*)apad + (size_t)row0 * D_;
  const __bf16* Bg = (const __bf16*)gub + ((size_t)e * TWOI_ + (size_t)ct * 64) * D_;
  const __bf16* Bu = Bg + (size_t)I_ * D_;

  int srow = lane >> 2;        // 0..15
  int skq  = (lane & 3) * 8;   // 0,8,16,24

  floatx4 zero = {0.f, 0.f, 0.f, 0.f};
  floatx4 accg[2][4], accu[2][4];
#pragma unroll
  for (int mi = 0; mi < 2; ++mi)
#pragma unroll
    for (int ni = 0; ni < 4; ++ni) { accg[mi][ni] = zero; accu[mi][ni] = zero; }

  int quad8 = (lane >> 4) * 8;
  int l16 = lane & 15;

  for (int k0 = 0; k0 < D_; k0 += 32) {
    gload16(A + (size_t)(wave * 16 + srow) * D_ + k0 + skq, &As[(wave * 16) * 32]);
    gload16(A + (size_t)(64 + wave * 16 + srow) * D_ + k0 + skq, &As[(64 + wave * 16) * 32]);
    gload16(Bg + (size_t)(wave * 16 + srow) * D_ + k0 + skq, &Bgs[(wave * 16) * 32]);
    gload16(Bu + (size_t)(wave * 16 + srow) * D_ + k0 + skq, &Bus[(wave * 16) * 32]);
    __syncthreads();
    bf16x8 af[2], bg[4], bu[4];
#pragma unroll
    for (int mi = 0; mi < 2; ++mi)
      af[mi] = *(const bf16x8*)&As[(wave * 32 + mi * 16 + l16) * 32 + quad8];
#pragma unroll
    for (int ni = 0; ni < 4; ++ni) {
      bg[ni] = *(const bf16x8*)&Bgs[(ni * 16 + l16) * 32 + quad8];
      bu[ni] = *(const bf16x8*)&Bus[(ni * 16 + l16) * 32 + quad8];
    }
#pragma unroll
    for (int mi = 0; mi < 2; ++mi)
#pragma unroll
      for (int ni = 0; ni < 4; ++ni) {
        accg[mi][ni] = __builtin_amdgcn_mfma_f32_16x16x32_bf16(af[mi], bg[ni], accg[mi][ni], 0, 0, 0);
        accu[mi][ni] = __builtin_amdgcn_mfma_f32_16x16x32_bf16(af[mi], bu[ni], accu[mi][ni], 0, 0, 0);
      }
    __syncthreads();
  }

  int quad = lane >> 4;
#pragma unroll
  for (int mi = 0; mi < 2; ++mi)
#pragma unroll
    for (int reg = 0; reg < 4; ++reg) {
      int r = wave * 32 + mi * 16 + quad * 4 + reg;
      if (r < nv) {
        float wgt = wpad[row0 + r];
        unsigned short* hrow = hpad + (size_t)(row0 + r) * I_ + (size_t)ct * 64;
#pragma unroll
        for (int ni = 0; ni < 4; ++ni) {
          float g = accg[mi][ni][reg];
          float u = accu[mi][ni][reg];
          float s = g / (1.f + __expf(-g));
          hrow[ni * 16 + l16] = f2bf(s * u * wgt);
        }
      }
    }
}

// -------------- GEMM2: out = h @ down^T, scatter rows --------------
__global__ __launch_bounds__(256) void k_gemm2(
    const unsigned short* __restrict__ hpad,
    const unsigned short* __restrict__ dnb,
    const int* __restrict__ meta,
    const int* __restrict__ perm,
    float* __restrict__ out) {
  int rt = blockIdx.x;
  if (rt >= meta[M_NT]) return;
  int ct = blockIdx.y;  // 0..15
  int e = meta[M_RTE + rt], row0 = meta[M_RTR + rt], nv = meta[M_RTV + rt];

  __shared__ __attribute__((aligned(16))) __bf16 As[128 * 32];
  __shared__ __attribute__((aligned(16))) __bf16 Bs[128 * 32];

  int tid = threadIdx.x;
  int lane = tid & 63;
  int wave = __builtin_amdgcn_readfirstlane(tid >> 6);
  int wm = wave >> 1, wn = wave & 1;

  const __bf16* A = (const __bf16*)hpad + (size_t)row0 * I_;
  const __bf16* B = (const __bf16*)dnb + ((size_t)e * D_ + (size_t)ct * 128) * I_;

  int srow = lane >> 2;
  int skq = (lane & 3) * 8;

  floatx4 zero = {0.f, 0.f, 0.f, 0.f};
  floatx4 acc[4][4];
#pragma unroll
  for (int mi = 0; mi < 4; ++mi)
#pragma unroll
    for (int ni = 0; ni < 4; ++ni) acc[mi][ni] = zero;

  int quad8 = (lane >> 4) * 8;
  int l16 = lane & 15;

  for (int k0 = 0; k0 < I_; k0 += 32) {
    gload16(A + (size_t)(wave * 16 + srow) * I_ + k0 + skq, &As[(wave * 16) * 32]);
    gload16(A + (size_t)(64 + wave * 16 + srow) * I_ + k0 + skq, &As[(64 + wave * 16) * 32]);
    gload16(B + (size_t)(wave * 16 + srow) * I_ + k0 + skq, &Bs[(wave * 16) * 32]);
    gload16(B + (size_t)(64 + wave * 16 + srow) * I_ + k0 + skq, &Bs[(64 + wave * 16) * 32]);
    __syncthreads();
    bf16x8 af[4], bfr[4];
#pragma unroll
    for (int mi = 0; mi < 4; ++mi)
      af[mi] = *(const bf16x8*)&As[(wm * 64 + mi * 16 + l16) * 32 + quad8];
#pragma unroll
    for (int ni = 0; ni < 4; ++ni)
      bfr[ni] = *(const bf16x8*)&Bs[(wn * 64 + ni * 16 + l16) * 32 + quad8];
#pragma unroll
    for (int mi = 0; mi < 4; ++mi)
#pragma unroll
      for (int ni = 0; ni < 4; ++ni)
        acc[mi][ni] = __builtin_amdgcn_mfma_f32_16x16x32_bf16(af[mi], bfr[ni], acc[mi][ni], 0, 0, 0);
    __syncthreads();
  }

  int quad = lane >> 4;
#pragma unroll
  for (int mi = 0; mi < 4; ++mi)
#pragma unroll
    for (int reg = 0; reg < 4; ++reg) {
      int r = wm * 64 + mi * 16 + quad * 4 + reg;
      if (r < nv) {
        int t = perm[row0 + r];
        float* orow = out + (size_t)t * D_ + (size_t)ct * 128 + wn * 64;
#pragma unroll
        for (int ni = 0; ni < 4; ++ni)
          orow[ni * 16 + l16] = acc[mi][ni][reg];
      }
    }
}

// -------------- fallback (tiny ws): correct but slow --------------
__global__ __launch_bounds__(256) void k_naive(
    const float* __restrict__ tokens, const int* __restrict__ ids,
    const float* __restrict__ w, const float* __restrict__ gu,
    const float* __restrict__ dn, float* __restrict__ out) {
  __shared__ float tok[D_];
  __shared__ float h[I_];
  int t = blockIdx.x;
  int e = ids[t];
  float wgt = w[t];
  for (int i = threadIdx.x; i < D_; i += 256) tok[i] = tokens[(size_t)t * D_ + i];
  __syncthreads();
  for (int j = threadIdx.x; j < I_; j += 256) {
    const float* wg = gu + ((size_t)e * TWOI_ + j) * D_;
    const float* wu = wg + (size_t)I_ * D_;
    float g = 0.f, u = 0.f;
    for (int k = 0; k < D_; ++k) { g += tok[k] * wg[k]; u += tok[k] * wu[k]; }
    h[j] = g / (1.f + __expf(-g)) * u * wgt;
  }
  __syncthreads();
  for (int d = threadIdx.x; d < D_; d += 256) {
    const float* wd = dn + ((size_t)e * D_ + d) * I_;
    float acc = 0.f;
    for (int k = 0; k < I_; ++k) acc += h[k] * wd[k];
    out[(size_t)t * D_ + d] = acc;
  }
}

extern "C" void kernel_launch(void* const* d_in, const int* in_sizes, int n_in,
                              void* d_out, int out_size, void* d_ws, size_t ws_size,
                              hipStream_t stream) {
  const float* tokens = (const float*)d_in[0];
  const int*   ids    = (const int*)d_in[1];
  const float* wts    = (const float*)d_in[2];
  const float* gu     = (const float*)d_in[3];
  const float* dn     = (const float*)d_in[4];
  float* out = (float*)d_out;

  if (ws_size < (size_t)WS_NEED) {
    k_naive<<<N_, 256, 0, stream>>>(tokens, ids, wts, gu, dn, out);
    return;
  }

  char* ws = (char*)d_ws;
  int* meta = (int*)ws;
  int* perm = (int*)(ws + OFF_PERM);
  float* wpad = (float*)(ws + OFF_WPAD);
  unsigned short* apad = (unsigned short*)(ws + OFF_APAD);
  unsigned short* hpad = (unsigned short*)(ws + OFF_HPAD);
  unsigned short* gub  = (unsigned short*)(ws + OFF_GU);
  unsigned short* dnb  = (unsigned short*)(ws + OFF_DN);

  hipMemsetAsync(meta, 0, 64, stream);                 // cnt + cur
  hipMemsetAsync(perm, 0xFF, MPAD * 4, stream);        // perm = -1
  k_hist<<<N_ / 256, 256, 0, stream>>>(ids, meta);
  k_meta<<<1, 1, 0, stream>>>(meta);
  k_scatter<<<N_ / 256, 256, 0, stream>>>(ids, wts, meta, perm, wpad);
  k_gather<<<MPAD, 256, 0, stream>>>(tokens, perm, apad);
  int ngu8 = E_ * TWOI_ * D_ / 8;
  int ndn8 = E_ * D_ * I_ / 8;
  k_cvt<<<(ngu8 + 255) / 256, 256, 0, stream>>>(gu, gub, ngu8);
  k_cvt<<<(ndn8 + 255) / 256, 256, 0, stream>>>(dn, dnb, ndn8);
  k_gemm1<<<dim3(MAXTILES, I_ / 64), 256, 0, stream>>>(apad, gub, wpad, meta, hpad);
  k_gemm2<<<dim3(MAXTILES, D_ / 128), 256, 0, stream>>>(hpad, dnb, meta, perm, out);
}

// Round 2
// 659.805 us; speedup vs baseline: 1.1455x; 1.1455x over previous
//
#include <hip/hip_runtime.h>
#include <stdint.h>

#define E_    8
#define D_    2048
#define I_    1408
#define TWOI_ 2816
#define N_    8192
#define BM    128
#define MAXTILES 72
#define MPAD  9216

typedef __bf16 bf16x8 __attribute__((ext_vector_type(8)));
typedef float  floatx4 __attribute__((ext_vector_type(4)));

// ---- meta layout (int offsets into ws) ----
#define M_CNT   0    // [8]
#define M_CUR   8    // [8]
#define M_PB    16   // padbase[8]
#define M_NT    24   // ntiles
#define M_RTE   32   // rt_expert[72]
#define M_RTR   104  // rt_row0[72]
#define M_RTV   176  // rt_nvalid[72]

// ---- ws byte offsets ----
#define OFF_PERM  4096ULL
#define OFF_WPAD  40960ULL
#define OFF_APAD  81920ULL
#define OFF_HPAD  37830656ULL
#define OFF_GU    63782912ULL
#define OFF_DN    156057600ULL
#define WS_NEED   202194944ULL

__device__ inline void gload16(const void* g, void* lds) {
  __builtin_amdgcn_global_load_lds(
      (__attribute__((address_space(1))) void*)g,
      (__attribute__((address_space(3))) void*)lds, 16, 0, 0);
}

__device__ inline unsigned short f2bf(float f) {
  unsigned int u = __builtin_bit_cast(unsigned int, f);
  u += 0x7fffu + ((u >> 16) & 1u);   // RNE; inputs finite
  return (unsigned short)(u >> 16);
}

// ---------------- routing (ballot-based: 8 atomics/wave, not 64) ----------------
__global__ void k_hist(const int* __restrict__ ids, int* meta) {
  int i = blockIdx.x * 256 + threadIdx.x;   // N_ divisible by 256: all lanes live
  int e = ids[i];
  int lane = threadIdx.x & 63;
  for (int ex = 0; ex < E_; ++ex) {
    unsigned long long m = __ballot(e == ex);
    if (lane == 0 && m) atomicAdd(&meta[M_CNT + ex], __popcll(m));
  }
}

__global__ void k_meta(int* meta) {
  if (threadIdx.x != 0) return;
  int padr = 0, tiles = 0;
  for (int e = 0; e < E_; ++e) {
    meta[M_PB + e] = padr;
    int c = meta[M_CNT + e];
    int nt = (c + BM - 1) / BM;
    for (int t = 0; t < nt; ++t) {
      meta[M_RTE + tiles] = e;
      meta[M_RTR + tiles] = padr + t * BM;
      int v = c - t * BM; if (v > BM) v = BM;
      meta[M_RTV + tiles] = v;
      tiles++;
    }
    padr += nt * BM;
  }
  meta[M_NT] = tiles;
}

__global__ void k_scatter(const int* __restrict__ ids, const float* __restrict__ w,
                          int* meta, int* perm, float* wpad) {
  int i = blockIdx.x * 256 + threadIdx.x;
  int e = ids[i];
  float wv = w[i];
  int lane = threadIdx.x & 63;
  for (int ex = 0; ex < E_; ++ex) {
    unsigned long long m = __ballot(e == ex);
    if (!m) continue;                       // m is wave-uniform
    int base = 0;
    if (lane == 0) base = atomicAdd(&meta[M_CUR + ex], __popcll(m));
    base = __shfl(base, 0);
    if (e == ex) {
      int r = meta[M_PB + ex] + base + __popcll(m & ((1ULL << lane) - 1ULL));
      perm[r] = i;
      wpad[r] = wv;
    }
  }
}

// -------------- gather tokens -> bf16 (permuted, padded) --------------
__global__ void k_gather(const float* __restrict__ tokens, const int* __restrict__ perm,
                         unsigned short* __restrict__ apad) {
  int r = blockIdx.x;
  int t = perm[r];
  if (t < 0) return;  // pad row: leave as-is (finite poison)
  const float4* src = (const float4*)(tokens + (size_t)t * D_);
  uint4* dst = (uint4*)(apad + (size_t)r * D_);
  int i = threadIdx.x;  // 256 threads x 8 floats = 2048
  float4 a = src[i * 2], b = src[i * 2 + 1];
  union { unsigned short s[8]; uint4 v; } pk;
  pk.s[0] = f2bf(a.x); pk.s[1] = f2bf(a.y); pk.s[2] = f2bf(a.z); pk.s[3] = f2bf(a.w);
  pk.s[4] = f2bf(b.x); pk.s[5] = f2bf(b.y); pk.s[6] = f2bf(b.z); pk.s[7] = f2bf(b.w);
  dst[i] = pk.v;
}

// -------------- fp32 -> bf16 weight convert --------------
__global__ void k_cvt(const float* __restrict__ src, unsigned short* __restrict__ dst, int n8) {
  int i = blockIdx.x * 256 + threadIdx.x;  // each handles 8 elements
  if (i >= n8) return;
  const float4* s4 = (const float4*)src;
  float4 a = s4[i * 2], b = s4[i * 2 + 1];
  union { unsigned short s[8]; uint4 v; } pk;
  pk.s[0] = f2bf(a.x); pk.s[1] = f2bf(a.y); pk.s[2] = f2bf(a.z); pk.s[3] = f2bf(a.w);
  pk.s[4] = f2bf(b.x); pk.s[5] = f2bf(b.y); pk.s[6] = f2bf(b.z); pk.s[7] = f2bf(b.w);
  ((uint4*)dst)[i] = pk.v;
}

// -------------- GEMM1: fc1 = A @ gate_up^T, fused SwiGLU -> h (bf16) --------------
// 1D grid, panel-swizzled: panel = 8 row-tiles; rt fastest within panel so each
// XCD (round-robin dispatch) keeps one 512KB A-tile L2-resident across all ct.
// BK=64 as two 32-wide LDS panels per barrier (keeps 64B row pitch + gload16
// contiguity; halves barrier drains).
__global__ __launch_bounds__(256) void k_gemm1(
    const unsigned short* __restrict__ apad,
    const unsigned short* __restrict__ gub,
    const float* __restrict__ wpad,
    const int* __restrict__ meta,
    unsigned short* __restrict__ hpad) {
  int bid = blockIdx.x;
  int panel = bid / 176;            // 22 ct * 8 rt
  int rem = bid - panel * 176;
  int ct = rem >> 3;                // 0..21
  int rt = panel * 8 + (rem & 7);
  if (rt >= meta[M_NT]) return;
  int e = meta[M_RTE + rt], row0 = meta[M_RTR + rt], nv = meta[M_RTV + rt];

  __shared__ __attribute__((aligned(16))) __bf16 As[2][BM * 32];
  __shared__ __attribute__((aligned(16))) __bf16 Bgs[2][64 * 32];
  __shared__ __attribute__((aligned(16))) __bf16 Bus[2][64 * 32];

  int tid = threadIdx.x;
  int lane = tid & 63;
  int wave = __builtin_amdgcn_readfirstlane(tid >> 6);

  const __bf16* A  = (const __bf16*)apad + (size_t)row0 * D_;
  const __bf16* Bg = (const __bf16*)gub + ((size_t)e * TWOI_ + (size_t)ct * 64) * D_;
  const __bf16* Bu = Bg + (size_t)I_ * D_;

  int srow = lane >> 2;        // 0..15
  int skq  = (lane & 3) * 8;   // 0,8,16,24

  floatx4 zero = {0.f, 0.f, 0.f, 0.f};
  floatx4 accg[2][4], accu[2][4];
#pragma unroll
  for (int mi = 0; mi < 2; ++mi)
#pragma unroll
    for (int ni = 0; ni < 4; ++ni) { accg[mi][ni] = zero; accu[mi][ni] = zero; }

  int quad8 = (lane >> 4) * 8;
  int l16 = lane & 15;

  for (int k0 = 0; k0 < D_; k0 += 64) {
#pragma unroll
    for (int p = 0; p < 2; ++p) {
      int kk = k0 + p * 32;
      gload16(A + (size_t)(wave * 16 + srow) * D_ + kk + skq, &As[p][(wave * 16) * 32]);
      gload16(A + (size_t)(64 + wave * 16 + srow) * D_ + kk + skq, &As[p][(64 + wave * 16) * 32]);
      gload16(Bg + (size_t)(wave * 16 + srow) * D_ + kk + skq, &Bgs[p][(wave * 16) * 32]);
      gload16(Bu + (size_t)(wave * 16 + srow) * D_ + kk + skq, &Bus[p][(wave * 16) * 32]);
    }
    __syncthreads();
#pragma unroll
    for (int p = 0; p < 2; ++p) {
      bf16x8 af[2], bg[4], bu[4];
#pragma unroll
      for (int mi = 0; mi < 2; ++mi)
        af[mi] = *(const bf16x8*)&As[p][(wave * 32 + mi * 16 + l16) * 32 + quad8];
#pragma unroll
      for (int ni = 0; ni < 4; ++ni) {
        bg[ni] = *(const bf16x8*)&Bgs[p][(ni * 16 + l16) * 32 + quad8];
        bu[ni] = *(const bf16x8*)&Bus[p][(ni * 16 + l16) * 32 + quad8];
      }
#pragma unroll
      for (int mi = 0; mi < 2; ++mi)
#pragma unroll
        for (int ni = 0; ni < 4; ++ni) {
          accg[mi][ni] = __builtin_amdgcn_mfma_f32_16x16x32_bf16(af[mi], bg[ni], accg[mi][ni], 0, 0, 0);
          accu[mi][ni] = __builtin_amdgcn_mfma_f32_16x16x32_bf16(af[mi], bu[ni], accu[mi][ni], 0, 0, 0);
        }
    }
    __syncthreads();
  }

  int quad = lane >> 4;
#pragma unroll
  for (int mi = 0; mi < 2; ++mi)
#pragma unroll
    for (int reg = 0; reg < 4; ++reg) {
      int r = wave * 32 + mi * 16 + quad * 4 + reg;
      if (r < nv) {
        float wgt = wpad[row0 + r];
        unsigned short* hrow = hpad + (size_t)(row0 + r) * I_ + (size_t)ct * 64;
#pragma unroll
        for (int ni = 0; ni < 4; ++ni) {
          float g = accg[mi][ni][reg];
          float u = accu[mi][ni][reg];
          float s = g / (1.f + __expf(-g));
          hrow[ni * 16 + l16] = f2bf(s * u * wgt);
        }
      }
    }
}

// -------------- GEMM2: out = h @ down^T, scatter rows --------------
__global__ __launch_bounds__(256) void k_gemm2(
    const unsigned short* __restrict__ hpad,
    const unsigned short* __restrict__ dnb,
    const int* __restrict__ meta,
    const int* __restrict__ perm,
    float* __restrict__ out) {
  int bid = blockIdx.x;
  int panel = bid / 128;            // 16 ct * 8 rt
  int rem = bid - panel * 128;
  int ct = rem >> 3;                // 0..15
  int rt = panel * 8 + (rem & 7);
  if (rt >= meta[M_NT]) return;
  int e = meta[M_RTE + rt], row0 = meta[M_RTR + rt], nv = meta[M_RTV + rt];

  __shared__ __attribute__((aligned(16))) __bf16 As[2][128 * 32];
  __shared__ __attribute__((aligned(16))) __bf16 Bs[2][128 * 32];

  int tid = threadIdx.x;
  int lane = tid & 63;
  int wave = __builtin_amdgcn_readfirstlane(tid >> 6);
  int wm = wave >> 1, wn = wave & 1;

  const __bf16* A = (const __bf16*)hpad + (size_t)row0 * I_;
  const __bf16* B = (const __bf16*)dnb + ((size_t)e * D_ + (size_t)ct * 128) * I_;

  int srow = lane >> 2;
  int skq = (lane & 3) * 8;

  floatx4 zero = {0.f, 0.f, 0.f, 0.f};
  floatx4 acc[4][4];
#pragma unroll
  for (int mi = 0; mi < 4; ++mi)
#pragma unroll
    for (int ni = 0; ni < 4; ++ni) acc[mi][ni] = zero;

  int quad8 = (lane >> 4) * 8;
  int l16 = lane & 15;

  for (int k0 = 0; k0 < I_; k0 += 64) {
#pragma unroll
    for (int p = 0; p < 2; ++p) {
      int kk = k0 + p * 32;
      gload16(A + (size_t)(wave * 16 + srow) * I_ + kk + skq, &As[p][(wave * 16) * 32]);
      gload16(A + (size_t)(64 + wave * 16 + srow) * I_ + kk + skq, &As[p][(64 + wave * 16) * 32]);
      gload16(B + (size_t)(wave * 16 + srow) * I_ + kk + skq, &Bs[p][(wave * 16) * 32]);
      gload16(B + (size_t)(64 + wave * 16 + srow) * I_ + kk + skq, &Bs[p][(64 + wave * 16) * 32]);
    }
    __syncthreads();
#pragma unroll
    for (int p = 0; p < 2; ++p) {
      bf16x8 af[4], bfr[4];
#pragma unroll
      for (int mi = 0; mi < 4; ++mi)
        af[mi] = *(const bf16x8*)&As[p][(wm * 64 + mi * 16 + l16) * 32 + quad8];
#pragma unroll
      for (int ni = 0; ni < 4; ++ni)
        bfr[ni] = *(const bf16x8*)&Bs[p][(wn * 64 + ni * 16 + l16) * 32 + quad8];
#pragma unroll
      for (int mi = 0; mi < 4; ++mi)
#pragma unroll
        for (int ni = 0; ni < 4; ++ni)
          acc[mi][ni] = __builtin_amdgcn_mfma_f32_16x16x32_bf16(af[mi], bfr[ni], acc[mi][ni], 0, 0, 0);
    }
    __syncthreads();
  }

  int quad = lane >> 4;
#pragma unroll
  for (int mi = 0; mi < 4; ++mi)
#pragma unroll
    for (int reg = 0; reg < 4; ++reg) {
      int r = wm * 64 + mi * 16 + quad * 4 + reg;
      if (r < nv) {
        int t = perm[row0 + r];
        float* orow = out + (size_t)t * D_ + (size_t)ct * 128 + wn * 64;
#pragma unroll
        for (int ni = 0; ni < 4; ++ni)
          orow[ni * 16 + l16] = acc[mi][ni][reg];
      }
    }
}

// -------------- fallback (tiny ws): correct but slow --------------
__global__ __launch_bounds__(256) void k_naive(
    const float* __restrict__ tokens, const int* __restrict__ ids,
    const float* __restrict__ w, const float* __restrict__ gu,
    const float* __restrict__ dn, float* __restrict__ out) {
  __shared__ float tok[D_];
  __shared__ float h[I_];
  int t = blockIdx.x;
  int e = ids[t];
  float wgt = w[t];
  for (int i = threadIdx.x; i < D_; i += 256) tok[i] = tokens[(size_t)t * D_ + i];
  __syncthreads();
  for (int j = threadIdx.x; j < I_; j += 256) {
    const float* wg = gu + ((size_t)e * TWOI_ + j) * D_;
    const float* wu = wg + (size_t)I_ * D_;
    float g = 0.f, u = 0.f;
    for (int k = 0; k < D_; ++k) { g += tok[k] * wg[k]; u += tok[k] * wu[k]; }
    h[j] = g / (1.f + __expf(-g)) * u * wgt;
  }
  __syncthreads();
  for (int d = threadIdx.x; d < D_; d += 256) {
    const float* wd = dn + ((size_t)e * D_ + d) * I_;
    float acc = 0.f;
    for (int k = 0; k < I_; ++k) acc += h[k] * wd[k];
    out[(size_t)t * D_ + d] = acc;
  }
}

extern "C" void kernel_launch(void* const* d_in, const int* in_sizes, int n_in,
                              void* d_out, int out_size, void* d_ws, size_t ws_size,
                              hipStream_t stream) {
  const float* tokens = (const float*)d_in[0];
  const int*   ids    = (const int*)d_in[1];
  const float* wts    = (const float*)d_in[2];
  const float* gu     = (const float*)d_in[3];
  const float* dn     = (const float*)d_in[4];
  float* out = (float*)d_out;

  if (ws_size < (size_t)WS_NEED) {
    k_naive<<<N_, 256, 0, stream>>>(tokens, ids, wts, gu, dn, out);
    return;
  }

  char* ws = (char*)d_ws;
  int* meta = (int*)ws;
  int* perm = (int*)(ws + OFF_PERM);
  float* wpad = (float*)(ws + OFF_WPAD);
  unsigned short* apad = (unsigned short*)(ws + OFF_APAD);
  unsigned short* hpad = (unsigned short*)(ws + OFF_HPAD);
  unsigned short* gub  = (unsigned short*)(ws + OFF_GU);
  unsigned short* dnb  = (unsigned short*)(ws + OFF_DN);

  hipMemsetAsync(meta, 0, 64, stream);                 // cnt + cur
  hipMemsetAsync(perm, 0xFF, MPAD * 4, stream);        // perm = -1
  k_hist<<<N_ / 256, 256, 0, stream>>>(ids, meta);
  k_meta<<<1, 1, 0, stream>>>(meta);
  k_scatter<<<N_ / 256, 256, 0, stream>>>(ids, wts, meta, perm, wpad);
  k_gather<<<MPAD, 256, 0, stream>>>(tokens, perm, apad);
  int ngu8 = E_ * TWOI_ * D_ / 8;
  int ndn8 = E_ * D_ * I_ / 8;
  k_cvt<<<(ngu8 + 255) / 256, 256, 0, stream>>>(gu, gub, ngu8);
  k_cvt<<<(ndn8 + 255) / 256, 256, 0, stream>>>(dn, dnb, ndn8);
  k_gemm1<<<9 * 176, 256, 0, stream>>>(apad, gub, wpad, meta, hpad);
  k_gemm2<<<9 * 128, 256, 0, stream>>>(hpad, dnb, meta, perm, out);
}